// Round 1
// baseline (188.963 us; speedup 1.0000x reference)
//
#include <hip/hip_runtime.h>

#define TOPK 32

// ---------------------------------------------------------------------------
// Kernel A: one wave (64 lanes) per (b,s).
//   detect[b,s] = relu( dot( base[b, pos[b,s], :], W[b,:] ) )
//   counts[b, pos[b,s]] += 1   (scatter multiplicity for the later add)
// ---------------------------------------------------------------------------
__global__ void detect_kernel(const float* __restrict__ base,
                              const int* __restrict__ pos,
                              const float* __restrict__ bw,
                              float* __restrict__ detect,
                              int* __restrict__ counts,
                              int S, int H) {
    int wid  = (blockIdx.x * blockDim.x + threadIdx.x) >> 6;  // global wave id = b*S+s
    int lane = threadIdx.x & 63;
    int b = wid / S;
    int s = wid - b * S;
    int p = pos[b * S + s];

    const float4* row = (const float4*)(base + ((size_t)b * S + p) * H);
    const float4* w4  = (const float4*)(bw + (size_t)b * H);
    int n4 = H >> 2;

    float acc = 0.f;
    for (int i = lane; i < n4; i += 64) {
        float4 v = row[i];
        float4 w = w4[i];
        acc += v.x * w.x + v.y * w.y + v.z * w.z + v.w * w.w;
    }
    // wave-64 reduction (deterministic tree)
    for (int off = 32; off > 0; off >>= 1)
        acc += __shfl_down(acc, off, 64);

    if (lane == 0) {
        detect[b * S + s] = fmaxf(acc, 0.f);
        atomicAdd(&counts[b * S + p], 1);
    }
}

// ---------------------------------------------------------------------------
// Kernel B: one block per batch. Exact lax.top_k semantics: 32 iterations of
// argmax with ties broken toward LOWER index (duplicated positions produce
// exact ties, so this matters). Marks winners with -inf, then writes
// non_topk (winners zeroed) and mean(topk).
// ---------------------------------------------------------------------------
__global__ void topk_kernel(const float* __restrict__ detect,
                            float* __restrict__ nontopk,
                            float* __restrict__ meanv,
                            int S) {
    extern __shared__ float vals[];      // S floats
    __shared__ float wval[4];
    __shared__ int   widx[4];

    int b = blockIdx.x;
    int t = threadIdx.x;                 // 256 threads

    for (int i = t; i < S; i += 256) vals[i] = detect[(size_t)b * S + i];
    __syncthreads();

    float sum = 0.f;                     // live only in thread 0
    for (int it = 0; it < TOPK; ++it) {
        float lv = -INFINITY;
        int   li = 0x7fffffff;
        for (int i = t; i < S; i += 256) {
            float v = vals[i];
            if (v > lv) { lv = v; li = i; }   // ascending scan keeps lowest idx on tie
        }
        for (int off = 32; off > 0; off >>= 1) {
            float ov = __shfl_down(lv, off, 64);
            int   oi = __shfl_down(li, off, 64);
            if (ov > lv || (ov == lv && oi < li)) { lv = ov; li = oi; }
        }
        int lane = t & 63, w = t >> 6;
        if (lane == 0) { wval[w] = lv; widx[w] = li; }
        __syncthreads();
        if (t == 0) {
            float bv = wval[0]; int bi = widx[0];
            for (int k = 1; k < 4; ++k)
                if (wval[k] > bv || (wval[k] == bv && widx[k] < bi)) { bv = wval[k]; bi = widx[k]; }
            sum += bv;
            vals[bi] = -INFINITY;
            if (it == TOPK - 1) meanv[b] = sum / (float)TOPK;
        }
        __syncthreads();
    }

    for (int i = t; i < S; i += 256) {
        float v = vals[i];
        nontopk[(size_t)b * S + i] = (v == -INFINITY) ? 0.f : v;
    }
}

// ---------------------------------------------------------------------------
// Kernel C: one block per output row (b,p).
//   mixed[b,p,:] = base[b,p,:] + counts[b,p] * mean[b] * W[b,:]
// ---------------------------------------------------------------------------
__global__ void mix_kernel(const float* __restrict__ base,
                           const float* __restrict__ bw,
                           const int* __restrict__ counts,
                           const float* __restrict__ meanv,
                           float* __restrict__ mixed,
                           int S, int H) {
    int row = blockIdx.x;                // b*S + p
    int b = row / S;
    float scale = (float)counts[row] * meanv[b];

    const float4* b4 = (const float4*)(base + (size_t)row * H);
    const float4* w4 = (const float4*)(bw + (size_t)b * H);
    float4*       o4 = (float4*)(mixed + (size_t)row * H);
    int n4 = H >> 2;

    for (int i = threadIdx.x; i < n4; i += blockDim.x) {
        float4 v = b4[i];
        float4 w = w4[i];
        v.x += scale * w.x;
        v.y += scale * w.y;
        v.z += scale * w.z;
        v.w += scale * w.w;
        o4[i] = v;
    }
}

// ---------------------------------------------------------------------------
extern "C" void kernel_launch(void* const* d_in, const int* in_sizes, int n_in,
                              void* d_out, int out_size, void* d_ws, size_t ws_size,
                              hipStream_t stream) {
    const float* base = (const float*)d_in[0];
    const int*   pos  = (const int*)d_in[1];
    const float* bw   = (const float*)d_in[2];

    long n0 = in_sizes[0];               // B*S*H
    long n1 = in_sizes[1];               // B*S
    long n2 = in_sizes[2];               // B*H
    int H = (int)(n0 / n1);
    int B = (int)(n2 / H);
    int S = (int)(n1 / B);

    float* out_mixed   = (float*)d_out;
    float* out_detect  = out_mixed + (size_t)B * S * H;
    float* out_nontopk = out_detect + (size_t)B * S;

    int*   counts = (int*)d_ws;
    float* meanv  = (float*)((char*)d_ws + (size_t)B * S * sizeof(int));

    hipMemsetAsync(counts, 0, (size_t)B * S * sizeof(int), stream);

    int nwaves = B * S;                  // one wave per (b,s)
    detect_kernel<<<nwaves / 4, 256, 0, stream>>>(base, pos, bw, out_detect, counts, S, H);
    topk_kernel<<<B, 256, (size_t)S * sizeof(float), stream>>>(out_detect, out_nontopk, meanv, S);
    mix_kernel<<<B * S, 256, 0, stream>>>(base, bw, counts, meanv, out_mixed, S, H);
}